// Round 6
// baseline (28975.873 us; speedup 1.0000x reference)
//
#include <hip/hip_runtime.h>

#define N_B 128
#define LSEQ 2048
#define HID 512

// ws float offsets
#define OFF_YT 0
#define OFF_H1F 262144     // h1 ring: 4 slots x 2 bg x 65536 u16 = 1MB
#define OFF_H2F 524288     // h2 ring: 1MB
#define OFF_FLAGS 786432   // byte flags: F1 128KB + F2 128KB

#define F1_BYTE_OFF 0
#define F2_BYTE_OFF (2048*2*32)

// LDS layout (bytes)
#define PSUM_OFF   131072      // 16KB psum (ih partials)
#define BOUNCE_OFF 147456      // 4KB h bounce
#define OUTP_OFF   151552      // 1KB out partials
#define WLIN_OFF   152576      // 2KB Wlin copy
#define LDS_BYTES  154624

typedef __attribute__((ext_vector_type(8))) short short8;
typedef __attribute__((ext_vector_type(4))) float f32x4;
typedef __attribute__((ext_vector_type(8))) unsigned short ushort8;

typedef __attribute__((address_space(1))) const unsigned int GU32;
typedef __attribute__((address_space(3))) unsigned int LU32;

__device__ __forceinline__ float sigm(float x){ return 1.0f/(1.0f + __expf(-x)); }
__device__ __forceinline__ float tanhf_fast(float x){
  float ax = fabsf(x);
  float e = __expf(2.0f*ax);
  float t = 1.0f - 2.0f/(e + 1.0f);   // overflow-safe
  return x < 0.0f ? -t : t;
}

__device__ __forceinline__ unsigned short f2bf(float x){    // RNE fp32->bf16
  unsigned u = __builtin_bit_cast(unsigned, x);
  u += 0x7fffu + ((u>>16)&1u);
  return (unsigned short)(u>>16);
}
__device__ __forceinline__ float bf2f(unsigned short h){
  unsigned u = ((unsigned)h)<<16;
  return __builtin_bit_cast(float, u);
}

__device__ __forceinline__ f32x4 mm(short8 a, short8 b, f32x4 c){
  return __builtin_amdgcn_mfma_f32_16x16x32_bf16(a, b, c, 0, 0, 0);
}

// ---- fence-free dataflow primitives (sc0sc1 data path, relaxed flags) ----
__device__ __forceinline__ void polld(unsigned* w){       // wait 4 byte-flags
  while (__hip_atomic_load(w, __ATOMIC_RELAXED, __HIP_MEMORY_SCOPE_AGENT) != 0x01010101u)
    __builtin_amdgcn_s_sleep(1);
}
__device__ __forceinline__ void setb(unsigned char* p){
  __hip_atomic_store(p, (unsigned char)1, __ATOMIC_RELAXED, __HIP_MEMORY_SCOPE_AGENT);
}
__device__ __forceinline__ void st128cc(unsigned short* p, ushort8 v){
  asm volatile("global_store_dwordx4 %0, %1, off sc0 sc1"
               :: "v"(p), "v"(v) : "memory");
}
#define DRAIN() asm volatile("s_waitcnt vmcnt(0)" ::: "memory")

// async stage 131072 bytes (hi+lo planes) global -> LDS buf0/buf1, linear
__device__ __forceinline__ void stage128(const void* g, unsigned char* smem, int tid){
  const char* gp = (const char*)g;
  #pragma unroll
  for (int i = 0; i < 16; ++i){
    unsigned o = (unsigned)i*8192u + (unsigned)tid*16u;
    __builtin_amdgcn_global_load_lds(
        (GU32*)(gp + o),
        (LU32*)(smem + (unsigned)i*8192u + (unsigned)(tid & ~63)*16u),
        16, 0, 0x11);
  }
}

// pack 16 A-fragments (hi & lo bf16) for one wave
__device__ __forceinline__ void apack(const float* __restrict__ W, int u_w, int l15, int hig,
                                      short8* whi, short8* wlo){
  const int m = l15;
  const int row = (m&3)*HID + u_w + (m>>2);
  const float* wp0 = W + row*HID + hig*8;
  #pragma unroll
  for (int kt = 0; kt < 16; ++kt){
    short8 h8, l8;
    #pragma unroll
    for (int j = 0; j < 8; ++j){
      float v = wp0[kt*32 + j];
      unsigned short hb = f2bf(v);
      h8[j] = (short)hb;
      l8[j] = (short)f2bf(v - bf2f(hb));
    }
    whi[kt] = h8; wlo[kt] = l8;
  }
}

// hi-plane products: Ahi*Bhi + Alo*Bhi   (128 MFMA)
__device__ __forceinline__ void kt_hi(const unsigned char* buf, const short8* whi, const short8* wlo,
                                      int hig, int l15, f32x4* acc){
  #pragma unroll
  for (int kt = 0; kt < 16; ++kt){
    const unsigned base = (unsigned)((kt*4+hig)*64)*16u;
    #pragma unroll
    for (int nt = 0; nt < 4; ++nt){
      short8 b = *(const short8*)(buf + base + (unsigned)(nt*16 + l15)*16u);
      acc[nt] = mm(whi[kt], b, acc[nt]);
      acc[nt] = mm(wlo[kt], b, acc[nt]);
    }
  }
}
// lo-plane product: Ahi*Blo   (64 MFMA)
__device__ __forceinline__ void kt_lo(const unsigned char* buf, const short8* whi,
                                      int hig, int l15, f32x4* acc){
  #pragma unroll
  for (int kt = 0; kt < 16; ++kt){
    const unsigned base = (unsigned)((kt*4+hig)*64)*16u;
    #pragma unroll
    for (int nt = 0; nt < 4; ++nt){
      short8 b = *(const short8*)(buf + base + (unsigned)(nt*16 + l15)*16u);
      acc[nt] = mm(whi[kt], b, acc[nt]);
    }
  }
}

// transpose y -> yT; zero ring slot 3 of h1,h2; zero flags (every launch)
__global__ void init_kernel(const float* __restrict__ y, float* __restrict__ ws){
  int idx = blockIdx.x*256 + threadIdx.x;
  if (idx < LSEQ*N_B){
    int t = idx >> 7, n = idx & 127;
    ws[OFF_YT + idx] = y[n*LSEQ + t];
  }
  if (idx < 65536){
    ((unsigned*)(ws + OFF_H1F))[196608 + idx] = 0u;   // slot 3, both bg
    ((unsigned*)(ws + OFF_H2F))[196608 + idx] = 0u;
    ((unsigned*)(ws + OFF_FLAGS))[idx] = 0u;          // 256KB flags
  }
}

__launch_bounds__(512)
__global__ void lstm_kernel(
    const float* __restrict__ yT,
    const float* __restrict__ Wih1, const float* __restrict__ Whh1,
    const float* __restrict__ bi1,  const float* __restrict__ bh1,
    const float* __restrict__ Wih2, const float* __restrict__ Whh2,
    const float* __restrict__ bi2,  const float* __restrict__ bh2,
    const float* __restrict__ Wlin, const float* __restrict__ blin,
    unsigned short* __restrict__ h1u, unsigned short* __restrict__ h2u,
    float* __restrict__ out, unsigned char* __restrict__ flagsB)
{
  __shared__ unsigned char smem[LDS_BYTES];
  unsigned char* bufA = smem;
  unsigned char* bufB = smem + 65536;
  unsigned short* bnc = (unsigned short*)(smem + BOUNCE_OFF);
  const int tid  = threadIdx.x;
  const int lane = tid & 63;
  const int wv   = __builtin_amdgcn_readfirstlane(tid >> 6);
  const int blk  = blockIdx.x;
  const int l15  = lane & 15, hig = lane >> 4;
  unsigned char* F1 = flagsB + F1_BYTE_OFF;
  unsigned char* F2 = flagsB + F2_BYTE_OFF;

  if (blk < 64){
    // ======== layer 1: 2bg x 32 blocks, 16 units/block, waves 0-3 compute ========
    const int bg = blk >> 5, ug = blk & 31;
    const int u0 = ug*16;
    const int u_w = u0 + (wv&3)*4;
    short8 whi[16], wlo[16];
    float bsum[4], wih[4];
    if (wv < 4){
      apack(Whh1, u_w, l15, hig, whi, wlo);
      #pragma unroll
      for (int r = 0; r < 4; ++r){
        int row = r*HID + u_w + hig;
        bsum[r] = bi1[row] + bh1[row];
        wih[r]  = Wih1[row];
      }
    }
    float c1[4] = {0.f,0.f,0.f,0.f};
    const int kl = (wv&3)*4 + hig;       // local k within block slice

    #pragma clang loop unroll(disable)
    for (int t = 0; t < LSEQ; ++t){
      if (t >= 1 && wv == 0 && lane < 8) polld((unsigned*)(F1 + ((t-1)*2+bg)*32) + lane);
      if (t >= 4 && wv == 1 && lane < 8) polld((unsigned*)(F2 + ((t-4)*2+bg)*32) + lane);
      __syncthreads();                                            // B0
      stage128(h1u + ((unsigned)(((t+3)&3)*2 + bg) << 16), smem, tid);
      float yv[4];
      #pragma unroll
      for (int nt = 0; nt < 4; ++nt) yv[nt] = yT[t*N_B + bg*64 + nt*16 + l15];
      __syncthreads();                                            // B1: staged
      if (wv < 4){
        f32x4 acc[4];
        #pragma unroll
        for (int nt = 0; nt < 4; ++nt) acc[nt] = (f32x4){0.f,0.f,0.f,0.f};
        kt_hi(bufA, whi, wlo, hig, l15, acc);
        kt_lo(bufB, whi, hig, l15, acc);
        #pragma unroll
        for (int nt = 0; nt < 4; ++nt){
          float gi = acc[nt][0] + bsum[0] + wih[0]*yv[nt];
          float gf = acc[nt][1] + bsum[1] + wih[1]*yv[nt];
          float gg = acc[nt][2] + bsum[2] + wih[2]*yv[nt];
          float go = acc[nt][3] + bsum[3] + wih[3]*yv[nt];
          float cn = sigm(gf)*c1[nt] + sigm(gi)*tanhf_fast(gg);
          c1[nt] = cn;
          float hn = sigm(go)*tanhf_fast(cn);
          unsigned e = (unsigned)(((kl>>3)*64 + nt*16 + l15)*8 + (kl&7));
          bnc[e]        = f2bf(hn);
          bnc[1024 + e] = f2bf(hn - bf2f(f2bf(hn)));
        }
      }
      __syncthreads();                                            // B2: bounce ready
      if (tid < 256){
        ushort8 v = *(const ushort8*)(bnc + tid*8);
        unsigned short* hd = h1u + ((unsigned)((t&3)*2 + bg) << 16);
        unsigned gofs = (unsigned)(u0>>3)*512u;
        unsigned short* dst = (tid < 128) ? (hd + gofs + tid*8)
                                          : (hd + 32768u + gofs + (tid-128)*8);
        st128cc(dst, v);
        DRAIN();
      }
      __syncthreads();                                            // B3: all stores at LLC
      if (tid == 0) setb(F1 + (t*2+bg)*32 + ug);                  // publish h1(t)
    }
  } else {
    // ======== layer 2 (+fused out): 2bg x 32 blocks, 16 units; mat0=ih, mat1=hh ========
    const int b2 = blk - 64, bg = b2 >> 5, j32 = b2 & 31;
    const int u0 = j32*16;
    const int mat = wv >> 2, mt = wv & 3;
    const int u_w = u0 + mt*4;
    short8 whi[16], wlo[16];
    apack(mat ? Whh2 : Wih2, u_w, l15, hig, whi, wlo);
    float bsum[4], c2[4] = {0.f,0.f,0.f,0.f};
    #pragma unroll
    for (int r = 0; r < 4; ++r){
      int row = r*HID + u_w + hig;
      bsum[r] = bi2[row] + bh2[row];
    }
    const int kl = mt*4 + hig;
    const float bl = blin[0];
    float* lwl  = (float*)(smem + WLIN_OFF);
    float* outp = (float*)(smem + OUTP_OFF);
    if (j32 == 0) lwl[tid] = Wlin[tid];   // 512 floats; barriers below order it

    #pragma clang loop unroll(disable)
    for (int t = 0; t <= LSEQ; ++t){
      const bool last = (t == LSEQ);
      if (last && j32 != 0) break;
      // polls: F1(t) early (wave0), F2(t-1) on wave4 (critical)
      if (!last && wv == 0 && lane < 8) polld((unsigned*)(F1 + (t*2+bg)*32) + lane);
      if (t >= 1 && wv == 4 && lane < 8) polld((unsigned*)(F2 + ((t-1)*2+bg)*32) + lane);
      __syncthreads();                                            // B0
      if (!last) stage128(h1u + ((unsigned)((t&3)*2 + bg) << 16), smem, tid);
      __syncthreads();                                            // B1: h1 staged
      if (!last && mat == 0){
        f32x4 acc[4];
        #pragma unroll
        for (int nt = 0; nt < 4; ++nt) acc[nt] = (f32x4){0.f,0.f,0.f,0.f};
        kt_hi(bufA, whi, wlo, hig, l15, acc);
        kt_lo(bufB, whi, hig, l15, acc);
        #pragma unroll
        for (int nt = 0; nt < 4; ++nt)
          *(f32x4*)(smem + PSUM_OFF + (unsigned)((mt*4+nt)*64 + lane)*16u) = acc[nt];
      }
      __syncthreads();                                            // B2: psum ready, bufs free
      stage128(h2u + ((unsigned)(((t+3)&3)*2 + bg) << 16), smem, tid);
      __syncthreads();                                            // B3: h2 staged
      if (!last && mat == 1){
        f32x4 acc[4];
        #pragma unroll
        for (int nt = 0; nt < 4; ++nt) acc[nt] = (f32x4){0.f,0.f,0.f,0.f};
        kt_hi(bufA, whi, wlo, hig, l15, acc);
        kt_lo(bufB, whi, hig, l15, acc);
        #pragma unroll
        for (int nt = 0; nt < 4; ++nt){
          f32x4 ps = *(const f32x4*)(smem + PSUM_OFF + (unsigned)((mt*4+nt)*64 + lane)*16u);
          float gi = acc[nt][0] + ps[0] + bsum[0];
          float gf = acc[nt][1] + ps[1] + bsum[1];
          float gg = acc[nt][2] + ps[2] + bsum[2];
          float go = acc[nt][3] + ps[3] + bsum[3];
          float cn = sigm(gf)*c2[nt] + sigm(gi)*tanhf_fast(gg);
          c2[nt] = cn;
          float hn = sigm(go)*tanhf_fast(cn);
          unsigned e = (unsigned)(((kl>>3)*64 + nt*16 + l15)*8 + (kl&7));
          bnc[e]        = f2bf(hn);
          bnc[1024 + e] = f2bf(hn - bf2f(f2bf(hn)));
        }
      }
      if (j32 == 0 && mat == 0 && t >= 1){
        // fused out(t-1) from staged h2(t-1): wave wv covers k in [wv*128, +128)
        float a = 0.f;
        #pragma unroll
        for (int ko = 0; ko < 16; ++ko){
          int k8 = wv*16 + ko;
          ushort8 hi8 = *(const ushort8*)(bufA + (unsigned)(k8*64 + lane)*16u);
          ushort8 lo8 = *(const ushort8*)(bufB + (unsigned)(k8*64 + lane)*16u);
          #pragma unroll
          for (int j = 0; j < 8; ++j)
            a += (bf2f((unsigned short)hi8[j]) + bf2f((unsigned short)lo8[j])) * lwl[k8*8 + j];
        }
        outp[wv*64 + lane] = a;
      }
      __syncthreads();                                            // B4: bounce+outp ready
      if (!last && tid >= 256){
        int i = tid - 256;
        ushort8 v = *(const ushort8*)(bnc + i*8);
        unsigned short* hd = h2u + ((unsigned)((t&3)*2 + bg) << 16);
        unsigned gofs = (unsigned)(u0>>3)*512u;
        unsigned short* dst = (i < 128) ? (hd + gofs + i*8)
                                        : (hd + 32768u + gofs + (i-128)*8);
        st128cc(dst, v);
        DRAIN();
      }
      if (j32 == 0 && t >= 1 && wv == 0){
        float s = bl + outp[lane] + outp[64+lane] + outp[128+lane] + outp[192+lane];
        out[(bg*64 + lane)*LSEQ + (t-1)] = s;
      }
      __syncthreads();                                            // B5: h2 stores drained
      if (!last && tid == 0) setb(F2 + (t*2+bg)*32 + j32);        // publish h2(t)
    }
  }
}

extern "C" void kernel_launch(void* const* d_in, const int* in_sizes, int n_in,
                              void* d_out, int out_size, void* d_ws, size_t ws_size,
                              hipStream_t stream){
  (void)in_sizes; (void)n_in; (void)out_size; (void)ws_size;
  const float* y    = (const float*)d_in[0];
  const float* Wih1 = (const float*)d_in[1];
  const float* Whh1 = (const float*)d_in[2];
  const float* bi1  = (const float*)d_in[3];
  const float* bh1  = (const float*)d_in[4];
  const float* Wih2 = (const float*)d_in[5];
  const float* Whh2 = (const float*)d_in[6];
  const float* bi2  = (const float*)d_in[7];
  const float* bh2  = (const float*)d_in[8];
  const float* Wlin = (const float*)d_in[9];
  const float* blin = (const float*)d_in[10];
  float* ws  = (float*)d_ws;
  float* out = (float*)d_out;

  hipLaunchKernelGGL(init_kernel, dim3(1024), dim3(256), 0, stream, y, ws);

  const float* yT = ws + OFF_YT;
  unsigned short* h1u = (unsigned short*)(ws + OFF_H1F);
  unsigned short* h2u = (unsigned short*)(ws + OFF_H2F);
  unsigned char* flagsB = (unsigned char*)(ws + OFF_FLAGS);

  void* args[] = { (void*)&yT, (void*)&Wih1, (void*)&Whh1, (void*)&bi1, (void*)&bh1,
                   (void*)&Wih2, (void*)&Whh2, (void*)&bi2, (void*)&bh2,
                   (void*)&Wlin, (void*)&blin, (void*)&h1u, (void*)&h2u,
                   (void*)&out, (void*)&flagsB };
  hipLaunchCooperativeKernel((void*)lstm_kernel, dim3(128), dim3(512), args, 0, stream);
}

// Round 7
// 24983.183 us; speedup vs baseline: 1.1598x; 1.1598x over previous
//
#include <hip/hip_runtime.h>

#define N_B 128
#define LSEQ 2048
#define HID 512

// ws float offsets
#define OFF_YT 0
#define OFF_H1F 262144     // h1 ring: 4 slots x 2 bg x 65536 u16 = 1MB
#define OFF_H2F 524288     // h2 ring: 1MB
#define OFF_FLAGS 786432   // byte flags: F1 128KB + F2 128KB

#define F1_BYTE_OFF 0
#define F2_BYTE_OFF (2048*2*32)

// LDS layout (bytes)
#define PSUM_OFF   131072      // 16KB psum (ih partials)
#define BOUNCE_OFF 147456      // 4KB h bounce
#define OUTP_OFF   151552      // 1KB out partials
#define WLIN_OFF   152576      // 2KB Wlin copy
#define LDS_BYTES  154624

typedef __attribute__((ext_vector_type(8))) short short8;
typedef __attribute__((ext_vector_type(4))) float f32x4;
typedef __attribute__((ext_vector_type(8))) unsigned short ushort8;

typedef __attribute__((address_space(1))) const unsigned int GU32;
typedef __attribute__((address_space(3))) unsigned int LU32;

__device__ __forceinline__ float sigm(float x){ return 1.0f/(1.0f + __expf(-x)); }
__device__ __forceinline__ float tanhf_fast(float x){
  float ax = fabsf(x);
  float e = __expf(2.0f*ax);
  float t = 1.0f - 2.0f/(e + 1.0f);   // overflow-safe
  return x < 0.0f ? -t : t;
}

__device__ __forceinline__ unsigned short f2bf(float x){    // RNE fp32->bf16
  unsigned u = __builtin_bit_cast(unsigned, x);
  u += 0x7fffu + ((u>>16)&1u);
  return (unsigned short)(u>>16);
}
__device__ __forceinline__ float bf2f(unsigned short h){
  unsigned u = ((unsigned)h)<<16;
  return __builtin_bit_cast(float, u);
}

__device__ __forceinline__ f32x4 mm(short8 a, short8 b, f32x4 c){
  return __builtin_amdgcn_mfma_f32_16x16x32_bf16(a, b, c, 0, 0, 0);
}

// ---- fence-free dataflow primitives ----
__device__ __forceinline__ void polld(unsigned* w){       // wait 4 byte-flags
  while (__hip_atomic_load(w, __ATOMIC_RELAXED, __HIP_MEMORY_SCOPE_AGENT) != 0x01010101u)
    __builtin_amdgcn_s_sleep(1);
}
__device__ __forceinline__ void setb(unsigned char* p){
  __hip_atomic_store(p, (unsigned char)1, __ATOMIC_RELAXED, __HIP_MEMORY_SCOPE_AGENT);
}
__device__ __forceinline__ void st128cc(unsigned short* p, ushort8 v){
  asm volatile("global_store_dwordx4 %0, %1, off sc0 sc1"
               :: "v"(p), "v"(v) : "memory");
}
#define DRAIN() asm volatile("s_waitcnt vmcnt(0)" ::: "memory")

// async stage 131072 bytes (hi+lo planes) global -> LDS bufA/bufB, linear
__device__ __forceinline__ void stage128(const void* g, unsigned char* smem, int tid){
  const char* gp = (const char*)g;
  #pragma unroll
  for (int i = 0; i < 16; ++i){
    unsigned o = (unsigned)i*8192u + (unsigned)tid*16u;
    __builtin_amdgcn_global_load_lds(
        (GU32*)(gp + o),
        (LU32*)(smem + (unsigned)i*8192u + (unsigned)(tid & ~63)*16u),
        16, 0, 0x11);
  }
}

// pack 16 A-fragments (hi & lo bf16) for one wave
__device__ __forceinline__ void apack(const float* __restrict__ W, int u_w, int l15, int hig,
                                      short8* whi, short8* wlo){
  const int m = l15;
  const int row = (m&3)*HID + u_w + (m>>2);
  const float* wp0 = W + row*HID + hig*8;
  #pragma unroll
  for (int kt = 0; kt < 16; ++kt){
    short8 h8, l8;
    #pragma unroll
    for (int j = 0; j < 8; ++j){
      float v = wp0[kt*32 + j];
      unsigned short hb = f2bf(v);
      h8[j] = (short)hb;
      l8[j] = (short)f2bf(v - bf2f(hb));
    }
    whi[kt] = h8; wlo[kt] = l8;
  }
}

// hi-plane products: Ahi*Bhi + Alo*Bhi   (128 MFMA)
__device__ __forceinline__ void kt_hi(const unsigned char* buf, const short8* whi, const short8* wlo,
                                      int hig, int l15, f32x4* acc){
  #pragma unroll
  for (int kt = 0; kt < 16; ++kt){
    const unsigned base = (unsigned)((kt*4+hig)*64)*16u;
    #pragma unroll
    for (int nt = 0; nt < 4; ++nt){
      short8 b = *(const short8*)(buf + base + (unsigned)(nt*16 + l15)*16u);
      acc[nt] = mm(whi[kt], b, acc[nt]);
      acc[nt] = mm(wlo[kt], b, acc[nt]);
    }
  }
}
// lo-plane product: Ahi*Blo   (64 MFMA)
__device__ __forceinline__ void kt_lo(const unsigned char* buf, const short8* whi,
                                      int hig, int l15, f32x4* acc){
  #pragma unroll
  for (int kt = 0; kt < 16; ++kt){
    const unsigned base = (unsigned)((kt*4+hig)*64)*16u;
    #pragma unroll
    for (int nt = 0; nt < 4; ++nt){
      short8 b = *(const short8*)(buf + base + (unsigned)(nt*16 + l15)*16u);
      acc[nt] = mm(whi[kt], b, acc[nt]);
    }
  }
}

// transpose y -> yT; zero ring slot 3 of h1,h2; zero flags (every launch)
__global__ void init_kernel(const float* __restrict__ y, float* __restrict__ ws){
  int idx = blockIdx.x*256 + threadIdx.x;
  if (idx < LSEQ*N_B){
    int t = idx >> 7, n = idx & 127;
    ws[OFF_YT + idx] = y[n*LSEQ + t];
  }
  if (idx < 65536){
    ((unsigned*)(ws + OFF_H1F))[196608 + idx] = 0u;   // slot 3, both bg
    ((unsigned*)(ws + OFF_H2F))[196608 + idx] = 0u;
    ((unsigned*)(ws + OFF_FLAGS))[idx] = 0u;          // 256KB flags
  }
}

__launch_bounds__(512)
__global__ void lstm_kernel(
    const float* __restrict__ yT,
    const float* __restrict__ Wih1, const float* __restrict__ Whh1,
    const float* __restrict__ bi1,  const float* __restrict__ bh1,
    const float* __restrict__ Wih2, const float* __restrict__ Whh2,
    const float* __restrict__ bi2,  const float* __restrict__ bh2,
    const float* __restrict__ Wlin, const float* __restrict__ blin,
    unsigned short* __restrict__ h1u, unsigned short* __restrict__ h2u,
    float* __restrict__ out, unsigned char* __restrict__ flagsB)
{
  __shared__ unsigned char smem[LDS_BYTES];
  unsigned char* bufA = smem;
  unsigned char* bufB = smem + 65536;
  unsigned short* bnc = (unsigned short*)(smem + BOUNCE_OFF);
  const int tid  = threadIdx.x;
  const int lane = tid & 63;
  const int wv   = __builtin_amdgcn_readfirstlane(tid >> 6);
  const int blk  = blockIdx.x;
  const int l15  = lane & 15, hig = lane >> 4;
  unsigned char* F1 = flagsB + F1_BYTE_OFF;
  unsigned char* F2 = flagsB + F2_BYTE_OFF;

  if (blk < 64){
    // ======== layer 1: 2bg x 32 blocks, 16 units/block, waves 0-3 compute ========
    const int bg = blk >> 5, ug = blk & 31;
    const int u0 = ug*16;
    const int u_w = u0 + (wv&3)*4;
    short8 whi[16], wlo[16];
    float bsum[4], wih[4];
    if (wv < 4){
      apack(Whh1, u_w, l15, hig, whi, wlo);
      #pragma unroll
      for (int r = 0; r < 4; ++r){
        int row = r*HID + u_w + hig;
        bsum[r] = bi1[row] + bh1[row];
        wih[r]  = Wih1[row];
      }
    }
    float c1[4] = {0.f,0.f,0.f,0.f};
    const int kl = (wv&3)*4 + hig;       // local unit within block slice

    #pragma clang loop unroll(disable)
    for (int t = 0; t < LSEQ; ++t){
      if (t >= 1 && wv == 0 && lane < 8) polld((unsigned*)(F1 + ((t-1)*2+bg)*32) + lane);
      if (t >= 4 && wv == 1 && lane < 8) polld((unsigned*)(F2 + ((t-4)*2+bg)*32) + lane);
      __syncthreads();                                            // B0
      stage128(h1u + ((unsigned)(((t+3)&3)*2 + bg) << 16), smem, tid);
      float yv[4];
      if (wv < 4){
        #pragma unroll
        for (int nt = 0; nt < 4; ++nt) yv[nt] = yT[t*N_B + bg*64 + nt*16 + l15];
      }
      __syncthreads();                                            // B1: staged
      if (wv < 4){
        f32x4 acc[4];
        #pragma unroll
        for (int nt = 0; nt < 4; ++nt) acc[nt] = (f32x4){0.f,0.f,0.f,0.f};
        kt_hi(bufA, whi, wlo, hig, l15, acc);
        kt_lo(bufB, whi, hig, l15, acc);
        #pragma unroll
        for (int nt = 0; nt < 4; ++nt){
          float gi = acc[nt][0] + bsum[0] + wih[0]*yv[nt];
          float gf = acc[nt][1] + bsum[1] + wih[1]*yv[nt];
          float gg = acc[nt][2] + bsum[2] + wih[2]*yv[nt];
          float go = acc[nt][3] + bsum[3] + wih[3]*yv[nt];
          float cn = sigm(gf)*c1[nt] + sigm(gi)*tanhf_fast(gg);
          c1[nt] = cn;
          float hn = sigm(go)*tanhf_fast(cn);
          unsigned short hb = f2bf(hn);
          unsigned e = (unsigned)(((kl>>3)*64 + nt*16 + l15)*8 + (kl&7));
          bnc[e]        = hb;
          bnc[1024 + e] = f2bf(hn - bf2f(hb));
        }
      }
      __syncthreads();                                            // B2: bounce ready
      if (tid < 256){
        ushort8 v = *(const ushort8*)(bnc + tid*8);
        unsigned short* hd = h1u + ((unsigned)((t&3)*2 + bg) << 16);
        unsigned gofs = (unsigned)(u0>>3)*512u;
        unsigned short* dst = (tid < 128) ? (hd + gofs + tid*8)
                                          : (hd + 32768u + gofs + (tid-128)*8);
        st128cc(dst, v);
      }
      DRAIN();
      __syncthreads();                                            // B3: stores at LLC
      if (tid == 0) setb(F1 + (t*2+bg)*32 + ug);                  // publish h1(t)
    }
  } else {
    // ======== layer 2 (+fused out): 2bg x 32 blocks, 16 units; mat0=ih, mat1=hh ========
    const int b2 = blk - 64, bg = b2 >> 5, j32 = b2 & 31;
    const int u0 = j32*16;
    const int mat = wv >> 2, mt = wv & 3;
    const int u_w = u0 + mt*4;
    short8 whi[16], wlo[16];
    apack(mat ? Whh2 : Wih2, u_w, l15, hig, whi, wlo);
    float bsum[4], c2[4] = {0.f,0.f,0.f,0.f};
    #pragma unroll
    for (int r = 0; r < 4; ++r){
      int row = r*HID + u_w + hig;
      bsum[r] = bi2[row] + bh2[row];
    }
    const int kl = mt*4 + hig;
    const float bl = blin[0];
    float* lwl  = (float*)(smem + WLIN_OFF);
    float* outp = (float*)(smem + OUTP_OFF);
    if (j32 == 0) lwl[tid] = Wlin[tid];   // 512 floats; first barrier orders it

    #pragma clang loop unroll(disable)
    for (int t = 0; t <= LSEQ; ++t){
      const bool last = (t == LSEQ);
      if (last && j32 != 0) break;
      // ---- off-critical part: h1(t) + ih ----
      if (!last && wv == 0 && lane < 8) polld((unsigned*)(F1 + (t*2+bg)*32) + lane);
      __syncthreads();                                            // B0
      if (!last) stage128(h1u + ((unsigned)((t&3)*2 + bg) << 16), smem, tid);
      __syncthreads();                                            // B1: h1 staged
      if (!last && mat == 0){
        f32x4 acc[4];
        #pragma unroll
        for (int nt = 0; nt < 4; ++nt) acc[nt] = (f32x4){0.f,0.f,0.f,0.f};
        kt_hi(bufA, whi, wlo, hig, l15, acc);
        kt_lo(bufB, whi, hig, l15, acc);
        #pragma unroll
        for (int nt = 0; nt < 4; ++nt)
          *(f32x4*)(smem + PSUM_OFF + (unsigned)((mt*4+nt)*64 + lane)*16u) = acc[nt];
      }
      // critical gate polled CONCURRENTLY with ih by wave 4 (mat==1, idle here)
      if (t >= 1 && wv == 4 && lane < 8) polld((unsigned*)(F2 + ((t-1)*2+bg)*32) + lane);
      __syncthreads();                                            // B2: psum ready; F2 seen
      // ---- critical part: h2(t-1) + hh ----
      stage128(h2u + ((unsigned)(((t+3)&3)*2 + bg) << 16), smem, tid);
      __syncthreads();                                            // B3: h2 staged
      if (!last && mat == 1){
        f32x4 acc[4];
        #pragma unroll
        for (int nt = 0; nt < 4; ++nt) acc[nt] = (f32x4){0.f,0.f,0.f,0.f};
        kt_hi(bufA, whi, wlo, hig, l15, acc);
        kt_lo(bufB, whi, hig, l15, acc);
        #pragma unroll
        for (int nt = 0; nt < 4; ++nt){
          f32x4 ps = *(const f32x4*)(smem + PSUM_OFF + (unsigned)((mt*4+nt)*64 + lane)*16u);
          float gi = acc[nt][0] + ps[0] + bsum[0];
          float gf = acc[nt][1] + ps[1] + bsum[1];
          float gg = acc[nt][2] + ps[2] + bsum[2];
          float go = acc[nt][3] + ps[3] + bsum[3];
          float cn = sigm(gf)*c2[nt] + sigm(gi)*tanhf_fast(gg);
          c2[nt] = cn;
          float hn = sigm(go)*tanhf_fast(cn);
          unsigned short hb = f2bf(hn);
          unsigned e = (unsigned)(((kl>>3)*64 + nt*16 + l15)*8 + (kl&7));
          bnc[e]        = hb;
          bnc[1024 + e] = f2bf(hn - bf2f(hb));
        }
      }
      if (j32 == 0 && mat == 0 && t >= 1){
        // fused out(t-1) from staged h2(t-1), on ih-waves (idle in this phase)
        float a = 0.f;
        #pragma unroll
        for (int ko = 0; ko < 16; ++ko){
          int k8 = wv*16 + ko;
          ushort8 hi8 = *(const ushort8*)(bufA + (unsigned)(k8*64 + lane)*16u);
          ushort8 lo8 = *(const ushort8*)(bufB + (unsigned)(k8*64 + lane)*16u);
          #pragma unroll
          for (int j = 0; j < 8; ++j)
            a += (bf2f((unsigned short)hi8[j]) + bf2f((unsigned short)lo8[j])) * lwl[k8*8 + j];
        }
        outp[wv*64 + lane] = a;
      }
      __syncthreads();                                            // B4: bounce+outp ready
      if (!last && tid < 256){
        ushort8 v = *(const ushort8*)(bnc + tid*8);
        unsigned short* hd = h2u + ((unsigned)((t&3)*2 + bg) << 16);
        unsigned gofs = (unsigned)(u0>>3)*512u;
        unsigned short* dst = (tid < 128) ? (hd + gofs + tid*8)
                                          : (hd + 32768u + gofs + (tid-128)*8);
        st128cc(dst, v);
      }
      if (j32 == 0 && t >= 1 && wv == 0){
        float s = bl + outp[lane] + outp[64+lane] + outp[128+lane] + outp[192+lane];
        out[(bg*64 + lane)*LSEQ + (t-1)] = s;
      }
      DRAIN();
      __syncthreads();                                            // B5: h2 stores drained
      if (!last && tid == 0) setb(F2 + (t*2+bg)*32 + j32);        // publish h2(t)
    }
  }
}

extern "C" void kernel_launch(void* const* d_in, const int* in_sizes, int n_in,
                              void* d_out, int out_size, void* d_ws, size_t ws_size,
                              hipStream_t stream){
  (void)in_sizes; (void)n_in; (void)out_size; (void)ws_size;
  const float* y    = (const float*)d_in[0];
  const float* Wih1 = (const float*)d_in[1];
  const float* Whh1 = (const float*)d_in[2];
  const float* bi1  = (const float*)d_in[3];
  const float* bh1  = (const float*)d_in[4];
  const float* Wih2 = (const float*)d_in[5];
  const float* Whh2 = (const float*)d_in[6];
  const float* bi2  = (const float*)d_in[7];
  const float* bh2  = (const float*)d_in[8];
  const float* Wlin = (const float*)d_in[9];
  const float* blin = (const float*)d_in[10];
  float* ws  = (float*)d_ws;
  float* out = (float*)d_out;

  hipLaunchKernelGGL(init_kernel, dim3(1024), dim3(256), 0, stream, y, ws);

  const float* yT = ws + OFF_YT;
  unsigned short* h1u = (unsigned short*)(ws + OFF_H1F);
  unsigned short* h2u = (unsigned short*)(ws + OFF_H2F);
  unsigned char* flagsB = (unsigned char*)(ws + OFF_FLAGS);

  void* args[] = { (void*)&yT, (void*)&Wih1, (void*)&Whh1, (void*)&bi1, (void*)&bh1,
                   (void*)&Wih2, (void*)&Whh2, (void*)&bi2, (void*)&bh2,
                   (void*)&Wlin, (void*)&blin, (void*)&h1u, (void*)&h2u,
                   (void*)&out, (void*)&flagsB };
  hipLaunchCooperativeKernel((void*)lstm_kernel, dim3(128), dim3(512), args, 0, stream);
}

// Round 8
// 16735.233 us; speedup vs baseline: 1.7314x; 1.4928x over previous
//
#include <hip/hip_runtime.h>

#define N_B 128
#define LSEQ 2048
#define HID 512
#define BGN 32

// ws float offsets
#define OFF_YT 0
#define OFF_H1F 262144     // h1 ring: 4 slots x 4 bg x 32768 u16 = 1MB
#define OFF_H2F 524288     // h2 ring: 1MB
#define OFF_FLAGS 786432

#define F1_BYTE_OFF 0
#define F2_BYTE_OFF 131136          // 2049*4*16 bytes
#define FLAG_DWORDS 98352           // (2049*64 + 2049*128)/4

// LDS byte offsets
#define BUFH1_OFF 0
#define BUFH2_OFF 65536
#define PSUM_OFF  131072            // 8KB
#define BOUNCE_OFF 139264           // 4KB (L1 uses 4KB, L2 2KB)
#define OUTP_OFF  143360            // 1KB
#define WLIN_OFF  144384            // 2KB
#define LDS_BYTES 146432

typedef __attribute__((ext_vector_type(8))) short short8;
typedef __attribute__((ext_vector_type(4))) float f32x4;
typedef __attribute__((ext_vector_type(8))) unsigned short ushort8;

typedef __attribute__((address_space(1))) const unsigned int GU32;
typedef __attribute__((address_space(3))) unsigned int LU32;

__device__ __forceinline__ float sigm(float x){ return 1.0f/(1.0f + __expf(-x)); }
__device__ __forceinline__ float tanhf_fast(float x){
  float ax = fabsf(x);
  float e = __expf(2.0f*ax);
  float t = 1.0f - 2.0f/(e + 1.0f);   // overflow-safe
  return x < 0.0f ? -t : t;
}

__device__ __forceinline__ unsigned short f2bf(float x){    // RNE fp32->bf16
  unsigned u = __builtin_bit_cast(unsigned, x);
  u += 0x7fffu + ((u>>16)&1u);
  return (unsigned short)(u>>16);
}
__device__ __forceinline__ float bf2f(unsigned short h){
  unsigned u = ((unsigned)h)<<16;
  return __builtin_bit_cast(float, u);
}

__device__ __forceinline__ f32x4 mm(short8 a, short8 b, f32x4 c){
  return __builtin_amdgcn_mfma_f32_16x16x32_bf16(a, b, c, 0, 0, 0);
}

// ---- fence-free dataflow primitives ----
__device__ __forceinline__ void polld(unsigned* w){       // wait 4 byte-flags
  while (__hip_atomic_load(w, __ATOMIC_RELAXED, __HIP_MEMORY_SCOPE_AGENT) != 0x01010101u)
    __builtin_amdgcn_s_sleep(1);
}
__device__ __forceinline__ void setb(unsigned char* p){
  __hip_atomic_store(p, (unsigned char)1, __ATOMIC_RELAXED, __HIP_MEMORY_SCOPE_AGENT);
}
__device__ __forceinline__ void st128cc(unsigned short* p, ushort8 v){
  asm volatile("global_store_dwordx4 %0, %1, off sc0 sc1"
               :: "v"(p), "v"(v) : "memory");
}
#define DRAIN() asm volatile("s_waitcnt vmcnt(0)" ::: "memory")

// async stage 65536 bytes (hi+lo planes of one bg tile) global -> LDS, linear
__device__ __forceinline__ void stage64(const void* g, unsigned char* dst, int tid){
  const char* gp = (const char*)g;
  #pragma unroll
  for (int i = 0; i < 8; ++i){
    unsigned o = (unsigned)i*8192u + (unsigned)tid*16u;
    __builtin_amdgcn_global_load_lds(
        (GU32*)(gp + o),
        (LU32*)(dst + (unsigned)i*8192u + (unsigned)(tid & ~63)*16u),
        16, 0, 0x11);
  }
}

// pack 16 A-fragments (hi & lo bf16) for one wave
__device__ __forceinline__ void apack(const float* __restrict__ W, int u_w, int l15, int hig,
                                      short8* whi, short8* wlo){
  const int m = l15;
  const int row = (m&3)*HID + u_w + (m>>2);
  const float* wp0 = W + row*HID + hig*8;
  #pragma unroll
  for (int kt = 0; kt < 16; ++kt){
    short8 h8, l8;
    #pragma unroll
    for (int j = 0; j < 8; ++j){
      float v = wp0[kt*32 + j];
      unsigned short hb = f2bf(v);
      h8[j] = (short)hb;
      l8[j] = (short)f2bf(v - bf2f(hb));
    }
    whi[kt] = h8; wlo[kt] = l8;
  }
}

// B tile layout in LDS: [k8=k/8][n<32][k&7] u16, fragment = 16B at ((kt*4+hig)*32 + nt*16+l15)*16
// hi-plane: Ahi*Bhi + Alo*Bhi (64 MFMA); lo-plane: Ahi*Blo (32 MFMA)
__device__ __forceinline__ void kt_hi(const unsigned char* buf, const short8* whi, const short8* wlo,
                                      int hig, int l15, f32x4* acc){
  #pragma unroll
  for (int kt = 0; kt < 16; ++kt){
    const unsigned base = (unsigned)(kt*4+hig)*512u;
    #pragma unroll
    for (int nt = 0; nt < 2; ++nt){
      short8 b = *(const short8*)(buf + base + (unsigned)(nt*16 + l15)*16u);
      acc[nt] = mm(whi[kt], b, acc[nt]);
      acc[nt] = mm(wlo[kt], b, acc[nt]);
    }
  }
}
__device__ __forceinline__ void kt_lo(const unsigned char* buf, const short8* whi,
                                      int hig, int l15, f32x4* acc){
  #pragma unroll
  for (int kt = 0; kt < 16; ++kt){
    const unsigned base = (unsigned)(kt*4+hig)*512u;
    #pragma unroll
    for (int nt = 0; nt < 2; ++nt){
      short8 b = *(const short8*)(buf + base + (unsigned)(nt*16 + l15)*16u);
      acc[nt] = mm(whi[kt], b, acc[nt]);
    }
  }
}

// transpose y -> yT; zero ring slot 3 of h1,h2; zero flags (every launch)
__global__ void init_kernel(const float* __restrict__ y, float* __restrict__ ws){
  int idx = blockIdx.x*256 + threadIdx.x;
  if (idx < LSEQ*N_B){
    int t = idx >> 7, n = idx & 127;
    ws[OFF_YT + idx] = y[n*LSEQ + t];
  }
  if (idx < 65536){
    ((unsigned*)(ws + OFF_H1F))[196608 + idx] = 0u;   // slot 3, all bg
    ((unsigned*)(ws + OFF_H2F))[196608 + idx] = 0u;
  }
  if (idx < FLAG_DWORDS) ((unsigned*)(ws + OFF_FLAGS))[idx] = 0u;
}

__launch_bounds__(512)
__global__ void lstm_kernel(
    const float* __restrict__ yT,
    const float* __restrict__ Wih1, const float* __restrict__ Whh1,
    const float* __restrict__ bi1,  const float* __restrict__ bh1,
    const float* __restrict__ Wih2, const float* __restrict__ Whh2,
    const float* __restrict__ bi2,  const float* __restrict__ bh2,
    const float* __restrict__ Wlin, const float* __restrict__ blin,
    unsigned short* __restrict__ h1u, unsigned short* __restrict__ h2u,
    float* __restrict__ out, unsigned char* __restrict__ flagsB)
{
  __shared__ unsigned char smem[LDS_BYTES];
  unsigned short* bnc = (unsigned short*)(smem + BOUNCE_OFF);
  const int tid  = threadIdx.x;
  const int lane = tid & 63;
  const int wv   = __builtin_amdgcn_readfirstlane(tid >> 6);
  const int blk  = blockIdx.x;
  const int l15  = lane & 15, hig = lane >> 4;
  unsigned char* F1 = flagsB + F1_BYTE_OFF;
  unsigned char* F2 = flagsB + F2_BYTE_OFF;

  if (blk < 64){
    // ======== layer 1: 4bg x 16 blocks, 32 units/block, 8 compute waves ========
    const int bg = blk >> 4, ug = blk & 15;
    const int u0 = ug*32;
    const int u_w = u0 + wv*4;
    short8 whi[16], wlo[16];
    apack(Whh1, u_w, l15, hig, whi, wlo);
    float bsum[4], wih[4];
    #pragma unroll
    for (int r = 0; r < 4; ++r){
      int row = r*HID + u_w + hig;
      bsum[r] = bi1[row] + bh1[row];
      wih[r]  = Wih1[row];
    }
    float c1[2] = {0.f, 0.f};
    const int ul = wv*4 + hig;

    #pragma clang loop unroll(disable)
    for (int t = 0; t < LSEQ; ++t){
      if (t >= 1 && wv == 0 && lane < 4) polld((unsigned*)(F1 + ((t-1)*4+bg)*16) + lane);
      if (t >= 4 && wv == 1 && lane < 8) polld((unsigned*)(F2 + ((t-4)*4+bg)*32) + lane);
      __syncthreads();                                            // B0
      stage64(h1u + ((unsigned)(((t+3)&3)*4 + bg) << 15), smem + BUFH1_OFF, tid);
      float yv[2];
      #pragma unroll
      for (int nt = 0; nt < 2; ++nt) yv[nt] = yT[t*N_B + bg*BGN + nt*16 + l15];
      __syncthreads();                                            // B1: staged
      f32x4 acc[2];
      acc[0] = (f32x4){0.f,0.f,0.f,0.f}; acc[1] = acc[0];
      kt_hi(smem + BUFH1_OFF, whi, wlo, hig, l15, acc);
      kt_lo(smem + BUFH1_OFF + 32768, whi, hig, l15, acc);
      #pragma unroll
      for (int nt = 0; nt < 2; ++nt){
        float gi = acc[nt][0] + bsum[0] + wih[0]*yv[nt];
        float gf = acc[nt][1] + bsum[1] + wih[1]*yv[nt];
        float gg = acc[nt][2] + bsum[2] + wih[2]*yv[nt];
        float go = acc[nt][3] + bsum[3] + wih[3]*yv[nt];
        float cn = sigm(gf)*c1[nt] + sigm(gi)*tanhf_fast(gg);
        c1[nt] = cn;
        float hn = sigm(go)*tanhf_fast(cn);
        unsigned short hb = f2bf(hn);
        unsigned e = (unsigned)(((ul>>3)*32 + nt*16 + l15)*8 + (ul&7));
        bnc[e]        = hb;
        bnc[1024 + e] = f2bf(hn - bf2f(hb));
      }
      __syncthreads();                                            // B2: bounce ready
      if (tid < 256){
        ushort8 v = *(const ushort8*)(bnc + tid*8);
        unsigned short* hd = h1u + ((unsigned)((t&3)*4 + bg) << 15);
        unsigned short* dst = (tid < 128) ? (hd + u0*32 + tid*8)
                                          : (hd + 16384u + u0*32 + (tid-128)*8);
        st128cc(dst, v);
      }
      DRAIN();
      __syncthreads();                                            // B3: stores at LLC
      if (tid == 0) setb(F1 + (t*4+bg)*16 + ug);                  // publish h1(t)
    }
  } else {
    // ======== layer 2 (+fused out): 4bg x 32 blocks, 16 units; mat0=ih, mat1=hh ========
    const int b2 = blk - 64, bg = b2 >> 5, j32 = b2 & 31;
    const int u0 = j32*16;
    const int mat = wv >> 2, mt = wv & 3;
    const int u_w = u0 + mt*4;
    short8 whi[16], wlo[16];
    apack(mat ? Whh2 : Wih2, u_w, l15, hig, whi, wlo);
    float bsum[4], c2[2] = {0.f, 0.f};
    #pragma unroll
    for (int r = 0; r < 4; ++r){
      int row = r*HID + u_w + hig;
      bsum[r] = bi2[row] + bh2[row];
    }
    const int ul = mt*4 + hig;
    const float bl = blin[0];
    float* lwl  = (float*)(smem + WLIN_OFF);
    float* outp = (float*)(smem + OUTP_OFF);
    if (j32 == 0) lwl[tid] = Wlin[tid];

    #pragma clang loop unroll(disable)
    for (int p = 1; p <= LSEQ + 1; ++p){
      const bool mainit = (p <= LSEQ);
      if (!mainit && j32 != 0) break;
      if (mainit && wv == 0 && lane < 4) polld((unsigned*)(F1 + ((p-1)*4+bg)*16) + lane);
      if (p >= 2 && wv == 4 && lane < 8) polld((unsigned*)(F2 + ((p-2)*4+bg)*32) + lane);
      __syncthreads();                                            // B0
      stage64(h2u + ((unsigned)(((p+2)&3)*4 + bg) << 15), smem + BUFH2_OFF, tid);
      if (mainit) stage64(h1u + ((unsigned)(((p+3)&3)*4 + bg) << 15), smem + BUFH1_OFF, tid);
      __syncthreads();                                            // B1: both staged
      f32x4 acc[2];
      acc[0] = (f32x4){0.f,0.f,0.f,0.f}; acc[1] = acc[0];
      if (mainit){
        if (mat == 0){
          kt_hi(smem + BUFH1_OFF, whi, wlo, hig, l15, acc);
          kt_lo(smem + BUFH1_OFF + 32768, whi, hig, l15, acc);
          #pragma unroll
          for (int nt = 0; nt < 2; ++nt)
            *(f32x4*)(smem + PSUM_OFF + (unsigned)((mt*2+nt)*64 + lane)*16u) = acc[nt];
        } else {
          kt_hi(smem + BUFH2_OFF, whi, wlo, hig, l15, acc);
          kt_lo(smem + BUFH2_OFF + 32768, whi, hig, l15, acc);
        }
      }
      __syncthreads();                                            // B2: psum ready
      if (mainit && mat == 1){
        #pragma unroll
        for (int nt = 0; nt < 2; ++nt){
          f32x4 ps = *(const f32x4*)(smem + PSUM_OFF + (unsigned)((mt*2+nt)*64 + lane)*16u);
          float gi = acc[nt][0] + ps[0] + bsum[0];
          float gf = acc[nt][1] + ps[1] + bsum[1];
          float gg = acc[nt][2] + ps[2] + bsum[2];
          float go = acc[nt][3] + ps[3] + bsum[3];
          float cn = sigm(gf)*c2[nt] + sigm(gi)*tanhf_fast(gg);
          c2[nt] = cn;
          float hn = sigm(go)*tanhf_fast(cn);
          unsigned short hb = f2bf(hn);
          unsigned e = (unsigned)(((ul>>3)*32 + nt*16 + l15)*8 + (ul&7));
          bnc[e]       = hb;
          bnc[512 + e] = f2bf(hn - bf2f(hb));
        }
      }
      if (j32 == 0 && p >= 2 && mat == 0){
        // fused out(p-2) partials from staged h2(p-2)
        const int h = lane >> 5, n = lane & 31;
        float a = 0.f;
        #pragma unroll
        for (int ko = 0; ko < 8; ++ko){
          int k8 = wv*16 + h*8 + ko;
          ushort8 hi8 = *(const ushort8*)(smem + BUFH2_OFF + (unsigned)(k8*32+n)*16u);
          ushort8 lo8 = *(const ushort8*)(smem + BUFH2_OFF + 32768u + (unsigned)(k8*32+n)*16u);
          #pragma unroll
          for (int j = 0; j < 8; ++j)
            a += (bf2f((unsigned short)hi8[j]) + bf2f((unsigned short)lo8[j])) * lwl[k8*8 + j];
        }
        outp[(wv*2+h)*32 + n] = a;
      }
      __syncthreads();                                            // B3: bounce+outp ready
      if (mainit && tid < 128){
        ushort8 v = *(const ushort8*)(bnc + tid*8);
        unsigned short* hd = h2u + ((unsigned)(((p+3)&3)*4 + bg) << 15);
        unsigned short* dst = (tid < 64) ? (hd + u0*32 + tid*8)
                                         : (hd + 16384u + u0*32 + (tid-64)*8);
        st128cc(dst, v);
      }
      if (j32 == 0 && p >= 2 && wv == 0 && lane < 32){
        float s = bl;
        #pragma unroll
        for (int i = 0; i < 8; ++i) s += outp[i*32 + lane];
        out[(bg*BGN + lane)*LSEQ + (p-2)] = s;
      }
      DRAIN();
      __syncthreads();                                            // B4: stores drained
      if (mainit && tid == 0) setb(F2 + ((p-1)*4+bg)*32 + j32);   // publish h2(p-1)
    }
  }
}

extern "C" void kernel_launch(void* const* d_in, const int* in_sizes, int n_in,
                              void* d_out, int out_size, void* d_ws, size_t ws_size,
                              hipStream_t stream){
  (void)in_sizes; (void)n_in; (void)out_size; (void)ws_size;
  const float* y    = (const float*)d_in[0];
  const float* Wih1 = (const float*)d_in[1];
  const float* Whh1 = (const float*)d_in[2];
  const float* bi1  = (const float*)d_in[3];
  const float* bh1  = (const float*)d_in[4];
  const float* Wih2 = (const float*)d_in[5];
  const float* Whh2 = (const float*)d_in[6];
  const float* bi2  = (const float*)d_in[7];
  const float* bh2  = (const float*)d_in[8];
  const float* Wlin = (const float*)d_in[9];
  const float* blin = (const float*)d_in[10];
  float* ws  = (float*)d_ws;
  float* out = (float*)d_out;

  hipLaunchKernelGGL(init_kernel, dim3(1024), dim3(256), 0, stream, y, ws);

  const float* yT = ws + OFF_YT;
  unsigned short* h1u = (unsigned short*)(ws + OFF_H1F);
  unsigned short* h2u = (unsigned short*)(ws + OFF_H2F);
  unsigned char* flagsB = (unsigned char*)(ws + OFF_FLAGS);

  void* args[] = { (void*)&yT, (void*)&Wih1, (void*)&Whh1, (void*)&bi1, (void*)&bh1,
                   (void*)&Wih2, (void*)&Whh2, (void*)&bi2, (void*)&bh2,
                   (void*)&Wlin, (void*)&blin, (void*)&h1u, (void*)&h2u,
                   (void*)&out, (void*)&flagsB };
  hipLaunchCooperativeKernel((void*)lstm_kernel, dim3(192), dim3(512), args, 0, stream);
}